// Round 8
// baseline (960.944 us; speedup 1.0000x reference)
//
#include <hip/hip_runtime.h>

#define IN_F  64
#define MID_F 128
#define OUT_F 32

typedef __bf16 bf16x8 __attribute__((ext_vector_type(8)));
typedef float  f32x4  __attribute__((ext_vector_type(4)));

static __device__ inline unsigned pack2(float a, float b) {
    unsigned short x = __builtin_bit_cast(unsigned short, (__bf16)a);
    unsigned short y = __builtin_bit_cast(unsigned short, (__bf16)b);
    return (unsigned)x | ((unsigned)y << 16);
}

// ---------------- weight prep: fragment-ordered bf16 (conflict-free LDS reads) ----------------
__global__ void prep_kernel(const float* __restrict__ W1,
                            const float* __restrict__ W2,
                            unsigned* __restrict__ wbuf) {
    const int t = threadIdx.x;   // 1024 threads
    // w1frag: 1024 uint4 at wbuf[0..16KB). item i: f=i>>6 (t1=f>>1,q=f&1), l=i&63.
    {
        const int i = t;
        const int f = i >> 6, l = i & 63;
        const int t1 = f >> 1, q = f & 1, lg = l >> 4, lr = l & 15;
        unsigned r[4];
        #pragma unroll
        for (int jj = 0; jj < 4; ++jj) {
            const int k0 = q * 32 + lg * 8 + 2 * jj;
            const float v0 = W1[(size_t)k0 * MID_F + t1 * 16 + lr];
            const float v1 = W1[(size_t)(k0 + 1) * MID_F + t1 * 16 + lr];
            r[jj] = pack2(v0, v1);
        }
        ((uint4*)wbuf)[i] = make_uint4(r[0], r[1], r[2], r[3]);
    }
    // w2frag: 512 uint4 at wbuf[16..24KB). custom k-map + output-column perm
    // (perm makes a lane own 8 contiguous output feats: lg*8..lg*8+7).
    if (t < 512) {
        const int i = t;
        const int f = i >> 6, l = i & 63;
        const int u = f >> 2, q2 = f & 3, lg = l >> 4, lr = l & 15;
        const int n = u * 16 + lr;
        const int pn = ((n >> 2) & 3) * 8 + (n >> 4) * 4 + (n & 3);
        unsigned r[4];
        #pragma unroll
        for (int jj = 0; jj < 4; ++jj) {
            const int j0 = 2 * jj, j1 = 2 * jj + 1;
            const int ka = q2 * 32 + 16 * (j0 >> 2) + lg * 4 + (j0 & 3);
            const int kb = q2 * 32 + 16 * (j1 >> 2) + lg * 4 + (j1 & 3);
            r[jj] = pack2(W2[(size_t)ka * OUT_F + pn], W2[(size_t)kb * OUT_F + pn]);
        }
        ((uint4*)wbuf)[1024 + i] = make_uint4(r[0], r[1], r[2], r[3]);
    }
}

// ---------------- fused streaming MLP + deferred-atomic scatter ----------------
// One wave = 16 consecutive rows/chunk. Swapped-operand MFMA: lane owns one
// row's 8 contiguous output feats. Each chunk's 8 atomics + 1 count atomic are
// DEFERRED one iteration: loads of chunk i issue first, then chunk i-1's
// atomics, then compute — so the atomic completion (vmcnt) drains under a full
// chunk of compute instead of gating the loop.
__global__ __launch_bounds__(256) void fused_mlp_scatter(
    const float* __restrict__ vecs,
    const int*   __restrict__ sidx,
    const unsigned* __restrict__ wbuf,
    const float* __restrict__ b1, const float* __restrict__ b2,
    float* __restrict__ osum, float* __restrict__ counts, int nrows)
{
    __shared__ __align__(16) __bf16 sW1F[16 * 64 * 8];   // 16 KB frag-ordered
    __shared__ __align__(16) __bf16 sW2F[8 * 64 * 8];    //  8 KB frag-ordered
    __shared__ __align__(16) float sB1[MID_F];
    __shared__ __align__(16) float sB2[OUT_F];

    const int tid = threadIdx.x;
    {   // linear 24 KB copy, coalesced, conflict-free
        const uint4* src = (const uint4*)wbuf;
        uint4* w1 = (uint4*)sW1F;
        uint4* w2 = (uint4*)sW2F;
        #pragma unroll
        for (int i = tid; i < 1024; i += 256) w1[i] = src[i];
        #pragma unroll
        for (int i = tid; i < 512; i += 256) w2[i] = src[1024 + i];
        if (tid < MID_F) sB1[tid] = b1[tid];
        if (tid < OUT_F) sB2[tid] = b2[tid];
    }
    __syncthreads();

    const int lane = tid & 63, wid = tid >> 6;
    const int lg = lane >> 4, lr = lane & 15;

    const int nchunk = nrows >> 4;

    // deferred atomic payload (per lane: row lr of previous chunk, feats lg*8..+7)
    f32x4 d0 = {0.f, 0.f, 0.f, 0.f}, d1v = {0.f, 0.f, 0.f, 0.f};
    int dseg = -1;

    for (int c = blockIdx.x * 4 + wid; c < nchunk; c += gridDim.x * 4) {
        const int myrow = (c << 4) + lr;

        // ---- issue this chunk's loads FIRST (vmcnt is in-order: these can be
        //      waited on without draining the atomics issued below) ----
        const float* xr = vecs + (size_t)myrow * IN_F + lg * 8;
        f32x4 x0a = *(const f32x4*)(xr);
        f32x4 x0b = *(const f32x4*)(xr + 4);
        f32x4 x1a = *(const f32x4*)(xr + 32);
        f32x4 x1b = *(const f32x4*)(xr + 36);
        const int seg = sidx[myrow];

        // ---- flush previous chunk's atomics (complete during compute below) ----
        if (dseg >= 0) {
            float* o = osum + (size_t)dseg * OUT_F + lg * 8;
            #pragma unroll
            for (int j = 0; j < 4; ++j) atomicAdd(o + j, d0[j]);
            #pragma unroll
            for (int j = 0; j < 4; ++j) atomicAdd(o + 4 + j, d1v[j]);
            if (lg == 0) atomicAdd(counts + dseg, 1.0f);
        }

        // ---- convert x -> bf16 A-frags ----
        bf16x8 a[2];
        #pragma unroll
        for (int j = 0; j < 4; ++j) {
            a[0][j] = (__bf16)x0a[j]; a[0][j + 4] = (__bf16)x0b[j];
            a[1][j] = (__bf16)x1a[j]; a[1][j + 4] = (__bf16)x1b[j];
        }

        // ---- layer 1 (swapped): lane owns h[row lr][feat t*16+lg*4+r] ----
        unsigned p[8][2];
        #pragma unroll
        for (int t = 0; t < 8; ++t) {
            bf16x8 w1a = *(const bf16x8*)&sW1F[((t * 2 + 0) * 64 + lane) * 8];
            bf16x8 w1b = *(const bf16x8*)&sW1F[((t * 2 + 1) * 64 + lane) * 8];
            f32x4 acc = *(const f32x4*)&sB1[t * 16 + lg * 4];
            acc = __builtin_amdgcn_mfma_f32_16x16x32_bf16(w1a, a[0], acc, 0, 0, 0);
            acc = __builtin_amdgcn_mfma_f32_16x16x32_bf16(w1b, a[1], acc, 0, 0, 0);
            p[t][0] = pack2(fmaxf(acc[0], 0.f), fmaxf(acc[1], 0.f));
            p[t][1] = pack2(fmaxf(acc[2], 0.f), fmaxf(acc[3], 0.f));
        }

        // ---- layer 2 (swapped, zero-shuffle): lane owns feats lg*8..lg*8+7 ----
        f32x4 acc2[2];
        acc2[0] = *(const f32x4*)&sB2[lg * 8];
        acc2[1] = *(const f32x4*)&sB2[lg * 8 + 4];
        #pragma unroll
        for (int q = 0; q < 4; ++q) {
            uint4 bi = make_uint4(p[2 * q][0], p[2 * q][1], p[2 * q + 1][0], p[2 * q + 1][1]);
            bf16x8 B = __builtin_bit_cast(bf16x8, bi);
            bf16x8 w2a = *(const bf16x8*)&sW2F[((0 * 4 + q) * 64 + lane) * 8];
            bf16x8 w2b = *(const bf16x8*)&sW2F[((1 * 4 + q) * 64 + lane) * 8];
            acc2[0] = __builtin_amdgcn_mfma_f32_16x16x32_bf16(w2a, B, acc2[0], 0, 0, 0);
            acc2[1] = __builtin_amdgcn_mfma_f32_16x16x32_bf16(w2b, B, acc2[1], 0, 0, 0);
        }

        // ---- defer this chunk's scatter to next iteration ----
        d0 = acc2[0]; d1v = acc2[1]; dseg = seg;
    }

    // epilogue flush
    if (dseg >= 0) {
        float* o = osum + (size_t)dseg * OUT_F + lg * 8;
        #pragma unroll
        for (int j = 0; j < 4; ++j) atomicAdd(o + j, d0[j]);
        #pragma unroll
        for (int j = 0; j < 4; ++j) atomicAdd(o + 4 + j, d1v[j]);
        if (lg == 0) atomicAdd(counts + dseg, 1.0f);
    }
}

__global__ __launch_bounds__(256) void finalize_kernel(
    float* __restrict__ osum, const float* __restrict__ counts, int total)
{
    int i = blockIdx.x * 256 + threadIdx.x;
    if (i < total) osum[i] = osum[i] / fmaxf(counts[i >> 5], 1.0f);
}

extern "C" void kernel_launch(void* const* d_in, const int* in_sizes, int n_in,
                              void* d_out, int out_size, void* d_ws, size_t ws_size,
                              hipStream_t stream)
{
    const float* vecs = (const float*)d_in[0];
    const int*   sidx = (const int*)d_in[1];
    const float* W1 = (const float*)d_in[3];
    const float* b1 = (const float*)d_in[4];
    const float* W2 = (const float*)d_in[5];
    const float* b2 = (const float*)d_in[6];
    float* osum = (float*)d_out;

    const int nrows = in_sizes[0] / IN_F;
    const int nseg  = out_size / OUT_F;

    // workspace: counts (nseg f32) + wbuf (24 KB)
    char* w = (char*)d_ws;
    float*    counts = (float*)w;
    unsigned* wbuf   = (unsigned*)(w + (((size_t)nseg * 4 + 255) & ~(size_t)255));

    hipMemsetAsync(osum,   0, (size_t)out_size * sizeof(float), stream);
    hipMemsetAsync(counts, 0, (size_t)nseg * sizeof(float), stream);

    prep_kernel<<<1, 1024, 0, stream>>>(W1, W2, wbuf);
    fused_mlp_scatter<<<1024, 256, 0, stream>>>(vecs, sidx, wbuf, b1, b2,
                                                osum, counts, nrows);
    finalize_kernel<<<(out_size + 255) / 256, 256, 0, stream>>>(osum, counts, out_size);
}

// Round 9
// 186.363 us; speedup vs baseline: 5.1563x; 5.1563x over previous
//
#include <hip/hip_runtime.h>

#define IN_F  64
#define MID_F 128
#define OUT_F 32

typedef __bf16 bf16x8 __attribute__((ext_vector_type(8)));
typedef float  f32x4  __attribute__((ext_vector_type(4)));

static __device__ inline unsigned pack2(float a, float b) {
    unsigned short x = __builtin_bit_cast(unsigned short, (__bf16)a);
    unsigned short y = __builtin_bit_cast(unsigned short, (__bf16)b);
    return (unsigned)x | ((unsigned)y << 16);
}

// ---------------- weight prep: fragment-ordered bf16 (conflict-free LDS reads) ----------------
// w1frag (layer 1, swapped orientation): A=W1^T. frag f=t*2+q, lane l:
//   elem j = W1[k = q*32 + lg*8 + j][t*16 + lr]
// w2frag (layer 2, STANDARD orientation with k-permutation pi):
//   pi(q,lg,j) = ((j>>2)*4 + q)*16 + lg*4 + (j&3)   (feature index into h)
//   frag f2 = u*4+q, lane l: elem j = W2[pi(q,lg,j)][u*16 + lr]
// The permutation makes the layer-2 A-operand exactly the lane's own packed
// layer-1 outputs (zero shuffle), while the D-layout is row=x-row, col=feature
// -> atomics coalesce as 4 segments x 64B contiguous per instruction.
__global__ void prep_kernel(const float* __restrict__ W1,
                            const float* __restrict__ W2,
                            unsigned* __restrict__ wbuf) {
    const int t = threadIdx.x;   // 1024 threads
    {
        const int i = t;
        const int f = i >> 6, l = i & 63;
        const int t1 = f >> 1, q = f & 1, lg = l >> 4, lr = l & 15;
        unsigned r[4];
        #pragma unroll
        for (int jj = 0; jj < 4; ++jj) {
            const int k0 = q * 32 + lg * 8 + 2 * jj;
            const float v0 = W1[(size_t)k0 * MID_F + t1 * 16 + lr];
            const float v1 = W1[(size_t)(k0 + 1) * MID_F + t1 * 16 + lr];
            r[jj] = pack2(v0, v1);
        }
        ((uint4*)wbuf)[i] = make_uint4(r[0], r[1], r[2], r[3]);
    }
    if (t < 512) {
        const int i = t;
        const int f = i >> 6, l = i & 63;
        const int u = f >> 2, q = f & 3, lg = l >> 4, lr = l & 15;
        const int n = u * 16 + lr;
        unsigned r[4];
        #pragma unroll
        for (int jj = 0; jj < 4; ++jj) {
            const int j0 = 2 * jj, j1 = 2 * jj + 1;
            const int ka = ((j0 >> 2) * 4 + q) * 16 + lg * 4 + (j0 & 3);
            const int kb = ((j1 >> 2) * 4 + q) * 16 + lg * 4 + (j1 & 3);
            r[jj] = pack2(W2[(size_t)ka * OUT_F + n], W2[(size_t)kb * OUT_F + n]);
        }
        ((uint4*)wbuf)[1024 + i] = make_uint4(r[0], r[1], r[2], r[3]);
    }
}

// ---------------- fused streaming MLP + coalesced deferred-atomic scatter ----------------
__global__ __launch_bounds__(256) void fused_mlp_scatter(
    const float* __restrict__ vecs,
    const int*   __restrict__ sidx,
    const unsigned* __restrict__ wbuf,
    const float* __restrict__ b1, const float* __restrict__ b2,
    float* __restrict__ osum, float* __restrict__ counts, int nrows)
{
    __shared__ __align__(16) __bf16 sW1F[16 * 64 * 8];   // 16 KB frag-ordered
    __shared__ __align__(16) __bf16 sW2F[8 * 64 * 8];    //  8 KB frag-ordered
    __shared__ __align__(16) float sB1[MID_F];
    __shared__ __align__(16) float sB2[OUT_F];

    const int tid = threadIdx.x;
    {   // linear 24 KB copy, coalesced, conflict-free
        const uint4* src = (const uint4*)wbuf;
        uint4* w1 = (uint4*)sW1F;
        uint4* w2 = (uint4*)sW2F;
        #pragma unroll
        for (int i = tid; i < 1024; i += 256) w1[i] = src[i];
        #pragma unroll
        for (int i = tid; i < 512; i += 256) w2[i] = src[1024 + i];
        if (tid < MID_F) sB1[tid] = b1[tid];
        if (tid < OUT_F) sB2[tid] = b2[tid];
    }
    __syncthreads();

    const int lane = tid & 63, wid = tid >> 6;
    const int lg = lane >> 4, lr = lane & 15;

    const int nchunk = nrows >> 4;

    // deferred scatter payload: lane owns preds[rows lg*4+0..3][feats lr, 16+lr]
    f32x4 d0 = {0.f, 0.f, 0.f, 0.f}, d1v = {0.f, 0.f, 0.f, 0.f};
    int4 dsegs = make_int4(0, 0, 0, 0);
    bool have = false;

    for (int c = blockIdx.x * 4 + wid; c < nchunk; c += gridDim.x * 4) {
        const int base = c << 4;

        // ---- issue this chunk's loads FIRST (oldest in vmcnt order) ----
        const float* xr = vecs + (size_t)(base + lr) * IN_F + lg * 8;
        f32x4 x0a = *(const f32x4*)(xr);
        f32x4 x0b = *(const f32x4*)(xr + 4);
        f32x4 x1a = *(const f32x4*)(xr + 32);
        f32x4 x1b = *(const f32x4*)(xr + 36);
        int4 segs = *(const int4*)(sidx + base + lg * 4);   // rows lg*4+0..3

        // ---- flush previous chunk's atomics (drain under this chunk's compute) ----
        if (have) {
            const int sa[4] = { dsegs.x, dsegs.y, dsegs.z, dsegs.w };
            #pragma unroll
            for (int r = 0; r < 4; ++r) {
                // 16 lanes (lr) x contiguous floats of one segment per lg: 4 x 64B
                float* o = osum + (size_t)sa[r] * OUT_F + lr;
                atomicAdd(o,      d0[r]);
                atomicAdd(o + 16, d1v[r]);
            }
            // one count per row; cndmask chain avoids runtime-indexed registers
            const int cs = (lr == 0) ? dsegs.x : (lr == 1) ? dsegs.y
                         : (lr == 2) ? dsegs.z : dsegs.w;
            if (lr < 4) atomicAdd(counts + cs, 1.0f);
        }

        // ---- convert x -> bf16 A-frags (k = q*32 + lg*8 + j) ----
        bf16x8 a[2];
        #pragma unroll
        for (int j = 0; j < 4; ++j) {
            a[0][j] = (__bf16)x0a[j]; a[0][j + 4] = (__bf16)x0b[j];
            a[1][j] = (__bf16)x1a[j]; a[1][j + 4] = (__bf16)x1b[j];
        }

        // ---- layer 1 (swapped): lane owns h[row lr][feat t*16+lg*4+reg] ----
        unsigned p[8][2];
        #pragma unroll
        for (int t = 0; t < 8; ++t) {
            bf16x8 w1a = *(const bf16x8*)&sW1F[((t * 2 + 0) * 64 + lane) * 8];
            bf16x8 w1b = *(const bf16x8*)&sW1F[((t * 2 + 1) * 64 + lane) * 8];
            f32x4 acc = *(const f32x4*)&sB1[t * 16 + lg * 4];
            acc = __builtin_amdgcn_mfma_f32_16x16x32_bf16(w1a, a[0], acc, 0, 0, 0);
            acc = __builtin_amdgcn_mfma_f32_16x16x32_bf16(w1b, a[1], acc, 0, 0, 0);
            p[t][0] = pack2(fmaxf(acc[0], 0.f), fmaxf(acc[1], 0.f));
            p[t][1] = pack2(fmaxf(acc[2], 0.f), fmaxf(acc[3], 0.f));
        }

        // ---- layer 2 (STANDARD orientation, zero-shuffle via pi):
        //      A2 = lane's own packed h words; D: row = x-row lg*4+reg, col = feat u*16+lr
        const float bz0 = sB2[lr], bz1 = sB2[16 + lr];
        f32x4 acc2[2];
        acc2[0] = { bz0, bz0, bz0, bz0 };
        acc2[1] = { bz1, bz1, bz1, bz1 };
        #pragma unroll
        for (int q = 0; q < 4; ++q) {
            uint4 bi = make_uint4(p[q][0], p[q][1], p[q + 4][0], p[q + 4][1]);
            bf16x8 A2 = __builtin_bit_cast(bf16x8, bi);
            bf16x8 w2a = *(const bf16x8*)&sW2F[((0 * 4 + q) * 64 + lane) * 8];
            bf16x8 w2b = *(const bf16x8*)&sW2F[((1 * 4 + q) * 64 + lane) * 8];
            acc2[0] = __builtin_amdgcn_mfma_f32_16x16x32_bf16(A2, w2a, acc2[0], 0, 0, 0);
            acc2[1] = __builtin_amdgcn_mfma_f32_16x16x32_bf16(A2, w2b, acc2[1], 0, 0, 0);
        }

        // ---- defer this chunk's scatter ----
        d0 = acc2[0]; d1v = acc2[1]; dsegs = segs; have = true;
    }

    // epilogue flush
    if (have) {
        const int sa[4] = { dsegs.x, dsegs.y, dsegs.z, dsegs.w };
        #pragma unroll
        for (int r = 0; r < 4; ++r) {
            float* o = osum + (size_t)sa[r] * OUT_F + lr;
            atomicAdd(o,      d0[r]);
            atomicAdd(o + 16, d1v[r]);
        }
        const int cs = (lr == 0) ? dsegs.x : (lr == 1) ? dsegs.y
                     : (lr == 2) ? dsegs.z : dsegs.w;
        if (lr < 4) atomicAdd(counts + cs, 1.0f);
    }
}

__global__ __launch_bounds__(256) void finalize_kernel(
    float* __restrict__ osum, const float* __restrict__ counts, int total)
{
    int i = blockIdx.x * 256 + threadIdx.x;
    if (i < total) osum[i] = osum[i] / fmaxf(counts[i >> 5], 1.0f);
}

extern "C" void kernel_launch(void* const* d_in, const int* in_sizes, int n_in,
                              void* d_out, int out_size, void* d_ws, size_t ws_size,
                              hipStream_t stream)
{
    const float* vecs = (const float*)d_in[0];
    const int*   sidx = (const int*)d_in[1];
    const float* W1 = (const float*)d_in[3];
    const float* b1 = (const float*)d_in[4];
    const float* W2 = (const float*)d_in[5];
    const float* b2 = (const float*)d_in[6];
    float* osum = (float*)d_out;

    const int nrows = in_sizes[0] / IN_F;
    const int nseg  = out_size / OUT_F;

    // workspace: counts (nseg f32) + wbuf (24 KB)
    char* w = (char*)d_ws;
    float*    counts = (float*)w;
    unsigned* wbuf   = (unsigned*)(w + (((size_t)nseg * 4 + 255) & ~(size_t)255));

    hipMemsetAsync(osum,   0, (size_t)out_size * sizeof(float), stream);
    hipMemsetAsync(counts, 0, (size_t)nseg * sizeof(float), stream);

    prep_kernel<<<1, 1024, 0, stream>>>(W1, W2, wbuf);
    fused_mlp_scatter<<<2048, 256, 0, stream>>>(vecs, sidx, wbuf, b1, b2,
                                                osum, counts, nrows);
    finalize_kernel<<<(out_size + 255) / 256, 256, 0, stream>>>(osum, counts, out_size);
}